// Round 1
// baseline (297.528 us; speedup 1.0000x reference)
//
#include <hip/hip_runtime.h>
#include <math.h>

#define BB 4
#define PP 24
#define NN 3072
#define SS 128

// fexp(x,p) = sign(x)*|x|^p   (sign(0)=0, matching jnp.sign)
__device__ __forceinline__ float fexp_f(float v, float p) {
    float m = powf(fabsf(v), p);
    float s = (v > 0.f) ? 1.f : ((v < 0.f) ? -1.f : 0.f);
    return s * m;
}

// fix(v) = where(v>0, 1, -1) * max(|v|, 1e-6)
__device__ __forceinline__ float fix_f(float v) {
    return ((v > 0.f) ? 1.f : -1.f) * fmaxf(fabsf(v), 1e-6f);
}

__global__ __launch_bounds__(256) void superdec_main(
    const float* __restrict__ pc,      // (B,P,N,3)
    const float* __restrict__ nrm,     // (B,P,N,3)
    const float* __restrict__ scale,   // (B,P,3)
    const float* __restrict__ shape,   // (B,P,2)
    const float* __restrict__ assign,  // (B,N,P)
    const float* __restrict__ etas,    // (B,P,S)
    const float* __restrict__ omegas,  // (B,P,S)
    float* __restrict__ ws)            // per-bp: 4 floats [pcl, cub, asum, prim2pcl]
{
    const int bp  = blockIdx.x;        // 0..95
    const int b   = bp / PP;
    const int p   = bp % PP;
    const int tid = threadIdx.x;

    __shared__ float4 Xs[SS];
    __shared__ float  red[256];

    const float a1 = scale[bp * 3 + 0];
    const float a2 = scale[bp * 3 + 1];
    const float a3 = scale[bp * 3 + 2];
    const float e1 = shape[bp * 2 + 0];
    const float e2 = shape[bp * 2 + 1];

    // ---- Stage 1: superquadric sample points X[s] into LDS ----
    if (tid < SS) {
        float eta = etas[bp * SS + tid];
        float omg = omegas[bp * SS + tid];
        eta = (eta == 0.f) ? 1e-6f : eta;
        omg = (omg == 0.f) ? 1e-6f : omg;
        float ce = cosf(eta), se = sinf(eta);
        float co = cosf(omg), so = sinf(omg);
        float fce = fexp_f(ce, e1);
        float x = a1 * fce * fexp_f(co, e2);
        float y = a2 * fce * fexp_f(so, e2);
        float z = a3 * fexp_f(se, e1);
        Xs[tid] = make_float4(fix_f(x), fix_f(y), fix_f(z), 0.f);
    }
    __syncthreads();

    // ---- Pass A: loop over n; min over s (pcl), cuboid dist, assign colsum ----
    float acc_pcl = 0.f, acc_cub = 0.f, acc_asum = 0.f;
    const float* pcb = pc  + (size_t)bp * NN * 3;
    const float* nrb = nrm + (size_t)bp * NN * 3;

    for (int n = tid; n < NN; n += 256) {
        const float px = pcb[n * 3 + 0];
        const float py = pcb[n * 3 + 1];
        const float pz = pcb[n * 3 + 2];
        const float am = assign[((size_t)b * NN + n) * PP + p];

        float dmin = 3.4e38f;
        #pragma unroll 8
        for (int s = 0; s < SS; ++s) {
            float4 xv = Xs[s];
            float dx = xv.x - px, dy = xv.y - py, dz = xv.z - pz;
            float d = fmaf(dx, dx, fmaf(dy, dy, dz * dz));
            dmin = fminf(dmin, d);
        }
        acc_pcl += dmin * am;

        // cuboid loss term
        const float nx = nrb[n * 3 + 0];
        const float ny = nrb[n * 3 + 1];
        const float nz = nrb[n * 3 + 2];
        // argmax over {-nx, nx, -ny, ny, -nz, nz}; strict > == jnp first-max rule
        float best = -nx; int idx = 0;
        if ( nx > best) { best =  nx; idx = 1; }
        if (-ny > best) { best = -ny; idx = 2; }
        if ( ny > best) { best =  ny; idx = 3; }
        if (-nz > best) { best = -nz; idx = 4; }
        if ( nz > best) { best =  nz; idx = 5; }
        const int c = idx >> 1;
        const float sc0 = a1, sc1 = a2, sc2 = a3;
        const float scc = (c == 0) ? sc0 : ((c == 1) ? sc1 : sc2);
        const float fv  = (idx & 1) ? scc : -scc;

        float d0, d1, d2;
        {
            float pr0 = (c == 0) ? fv : fminf(fmaxf(px, -sc0), sc0);
            float pr1 = (c == 1) ? fv : fminf(fmaxf(py, -sc1), sc1);
            float pr2 = (c == 2) ? fv : fminf(fmaxf(pz, -sc2), sc2);
            d0 = pr0 - px; d1 = pr1 - py; d2 = pr2 - pz;
        }
        const float dcub = fmaf(d0, d0, fmaf(d1, d1, d2 * d2));
        acc_cub  += dcub * am;
        acc_asum += am;
    }

    // ---- block-sum the three accumulators ----
    float sum_pcl, sum_cub, sum_asum;
    {
        red[tid] = acc_pcl; __syncthreads();
        for (int off = 128; off > 0; off >>= 1) {
            if (tid < off) red[tid] += red[tid + off];
            __syncthreads();
        }
        sum_pcl = red[0]; __syncthreads();

        red[tid] = acc_cub; __syncthreads();
        for (int off = 128; off > 0; off >>= 1) {
            if (tid < off) red[tid] += red[tid + off];
            __syncthreads();
        }
        sum_cub = red[0]; __syncthreads();

        red[tid] = acc_asum; __syncthreads();
        for (int off = 128; off > 0; off >>= 1) {
            if (tid < off) red[tid] += red[tid + off];
            __syncthreads();
        }
        sum_asum = red[0]; __syncthreads();
    }

    // ---- Pass B: min over n for each s (prim2pcl) ----
    {
        const int s    = tid & (SS - 1);
        const int half = tid >> 7;            // 0 or 1
        const float4 xv = Xs[s];
        float m = 3.4e38f;
        const int n0 = half * (NN / 2);
        const int n1 = n0 + (NN / 2);
        for (int n = n0; n < n1; ++n) {
            float px = pcb[n * 3 + 0];
            float py = pcb[n * 3 + 1];
            float pz = pcb[n * 3 + 2];
            float dx = xv.x - px, dy = xv.y - py, dz = xv.z - pz;
            float d = fmaf(dx, dx, fmaf(dy, dy, dz * dz));
            m = fminf(m, d);
        }
        red[tid] = m; __syncthreads();
        float mm = 0.f;
        if (tid < SS) mm = fminf(red[tid], red[tid + SS]);
        __syncthreads();
        red[tid] = (tid < SS) ? mm : 0.f;
        __syncthreads();
        for (int off = 64; off > 0; off >>= 1) {
            if (tid < off) red[tid] += red[tid + off];
            __syncthreads();
        }
        if (tid == 0) {
            ws[bp * 4 + 0] = sum_pcl;
            ws[bp * 4 + 1] = sum_cub;
            ws[bp * 4 + 2] = sum_asum;
            ws[bp * 4 + 3] = red[0] / (float)SS;   // prim2pcl[b,p]
        }
    }
}

__global__ __launch_bounds__(128) void superdec_final(
    const float* __restrict__ ws,
    const float* __restrict__ exist,   // (B,P,1)
    float* __restrict__ out)
{
    __shared__ float s_pcl[96], s_cub[96], s_pe[96], s_e[96], s_bce[96], s_sq[96];
    const int t = threadIdx.x;
    if (t < BB * PP) {
        float pclv   = ws[t * 4 + 0];
        float cubv   = ws[t * 4 + 1];
        float colsum = ws[t * 4 + 2];
        float prim   = ws[t * 4 + 3];
        float e = exist[t];
        float gt = (colsum > 24.0f) ? 1.f : 0.f;
        s_pcl[t] = pclv;
        s_cub[t] = cubv;
        s_pe[t]  = prim * e;
        s_e[t]   = e;
        s_bce[t] = gt * logf(e) + (1.f - gt) * log1pf(-e);
        s_sq[t]  = sqrtf(colsum / (float)NN + 0.01f);
    }
    __syncthreads();
    if (t == 0) {
        float pcl_sum = 0.f, cub_sum = 0.f, bce_sum = 0.f;
        for (int i = 0; i < BB * PP; ++i) {
            pcl_sum += s_pcl[i]; cub_sum += s_cub[i]; bce_sum += s_bce[i];
        }
        float prim_loss = 0.f, sps = 0.f;
        for (int b = 0; b < BB; ++b) {
            float pe = 0.f, ee = 0.f, sq = 0.f;
            for (int p = 0; p < PP; ++p) {
                int i = b * PP + p;
                pe += s_pe[i]; ee += s_e[i]; sq += s_sq[i];
            }
            prim_loss += pe / (ee + 1e-6f);
            float mb = sq / (float)PP;
            sps += mb * mb;
        }
        prim_loss /= (float)BB;
        sps       /= (float)BB;
        float pcl_loss = pcl_sum / (float)(BB * NN);
        float cub      = cub_sum / (float)(BB * NN);
        float bce      = -bce_sum / (float)(BB * PP);
        out[0] = 0.1f * cub + 1.0f * (pcl_loss + prim_loss) + 0.01f * bce + 0.01f * sps;
    }
}

extern "C" void kernel_launch(void* const* d_in, const int* in_sizes, int n_in,
                              void* d_out, int out_size, void* d_ws, size_t ws_size,
                              hipStream_t stream) {
    const float* pc     = (const float*)d_in[0];
    const float* nrm    = (const float*)d_in[1];
    const float* scale  = (const float*)d_in[2];
    const float* shape  = (const float*)d_in[3];
    const float* exist  = (const float*)d_in[4];
    const float* assign = (const float*)d_in[5];
    const float* etas   = (const float*)d_in[6];
    const float* omegas = (const float*)d_in[7];
    float* ws  = (float*)d_ws;
    float* out = (float*)d_out;

    superdec_main<<<BB * PP, 256, 0, stream>>>(pc, nrm, scale, shape, assign, etas, omegas, ws);
    superdec_final<<<1, 128, 0, stream>>>(ws, exist, out);
}

// Round 2
// 101.483 us; speedup vs baseline: 2.9318x; 2.9318x over previous
//
#include <hip/hip_runtime.h>
#include <math.h>

#define BB 4
#define PP 24
#define NN 3072
#define SS 128
#define NSPLIT 12
#define CHUNK 256            // NN / NSPLIT

// ws layout (floats):
//   X region:    [0, 49152)                96*128 float4 sample points
//   partials:    [49152, 49152+152064)     per (bp,split): 128 s-mins + pcl,cub,asum, stride 132
//   bp results:  [201216, 201216+384)      per bp: pcl,cub,asum,prim
#define WS_X      0
#define WS_PART   49152
#define PART_STRIDE 132
#define WS_BP     201216

__device__ __forceinline__ float fexp_f(float v, float p) {
    float m = powf(fabsf(v), p);
    float s = (v > 0.f) ? 1.f : ((v < 0.f) ? -1.f : 0.f);
    return s * m;
}
__device__ __forceinline__ float fix_f(float v) {
    return ((v > 0.f) ? 1.f : -1.f) * fmaxf(fabsf(v), 1e-6f);
}
__device__ __forceinline__ float wave_sum(float v) {
    #pragma unroll
    for (int off = 32; off > 0; off >>= 1) v += __shfl_down(v, off);
    return v;
}

// ---- Kernel 1: superquadric sample points (96 blocks x 128 threads) ----
__global__ __launch_bounds__(128) void superdec_sample(
    const float* __restrict__ scale, const float* __restrict__ shape,
    const float* __restrict__ etas, const float* __restrict__ omegas,
    float* __restrict__ ws)
{
    const int bp = blockIdx.x;
    const int s  = threadIdx.x;
    const float a1 = scale[bp * 3 + 0];
    const float a2 = scale[bp * 3 + 1];
    const float a3 = scale[bp * 3 + 2];
    const float e1 = shape[bp * 2 + 0];
    const float e2 = shape[bp * 2 + 1];
    float eta = etas[bp * SS + s];
    float omg = omegas[bp * SS + s];
    eta = (eta == 0.f) ? 1e-6f : eta;
    omg = (omg == 0.f) ? 1e-6f : omg;
    float ce = cosf(eta), se = sinf(eta);
    float co = cosf(omg), so = sinf(omg);
    float fce = fexp_f(ce, e1);
    float x = a1 * fce * fexp_f(co, e2);
    float y = a2 * fce * fexp_f(so, e2);
    float z = a3 * fexp_f(se, e1);
    float4* X = (float4*)(ws + WS_X);
    X[bp * SS + s] = make_float4(fix_f(x), fix_f(y), fix_f(z), 0.f);
}

// ---- Kernel 2: main (96*NSPLIT blocks x 256 threads) ----
__global__ __launch_bounds__(256) void superdec_main(
    const float* __restrict__ pc, const float* __restrict__ nrm,
    const float* __restrict__ scale, const float* __restrict__ assign,
    float* __restrict__ ws)
{
    const int blk   = blockIdx.x;
    const int bp    = blk / NSPLIT;
    const int split = blk % NSPLIT;
    const int b     = bp / PP;
    const int p     = bp % PP;
    const int tid   = threadIdx.x;
    const int n0    = split * CHUNK;

    __shared__ float4 Xs[SS];
    __shared__ float4 Pts[CHUNK];
    __shared__ float  red[CHUNK];
    __shared__ float  wsum[12];

    const float sc0 = scale[bp * 3 + 0];
    const float sc1 = scale[bp * 3 + 1];
    const float sc2 = scale[bp * 3 + 2];

    // stage sample points and this chunk's points
    const float4* Xg = (const float4*)(ws + WS_X);
    if (tid < SS) Xs[tid] = Xg[bp * SS + tid];

    const float* pcb = pc + ((size_t)bp * NN + n0) * 3;
    const float px = pcb[tid * 3 + 0];
    const float py = pcb[tid * 3 + 1];
    const float pz = pcb[tid * 3 + 2];
    Pts[tid] = make_float4(px, py, pz, 0.f);
    __syncthreads();

    // ---- Pass A: min over s for this thread's point ----
    float m0 = 3.4e38f, m1 = 3.4e38f, m2 = 3.4e38f, m3 = 3.4e38f;
    #pragma unroll 4
    for (int s = 0; s < SS; s += 4) {
        float4 x0 = Xs[s + 0];
        float4 x1 = Xs[s + 1];
        float4 x2 = Xs[s + 2];
        float4 x3 = Xs[s + 3];
        float dx, dy, dz, d;
        dx = x0.x - px; dy = x0.y - py; dz = x0.z - pz;
        d = fmaf(dx, dx, fmaf(dy, dy, dz * dz)); m0 = fminf(m0, d);
        dx = x1.x - px; dy = x1.y - py; dz = x1.z - pz;
        d = fmaf(dx, dx, fmaf(dy, dy, dz * dz)); m1 = fminf(m1, d);
        dx = x2.x - px; dy = x2.y - py; dz = x2.z - pz;
        d = fmaf(dx, dx, fmaf(dy, dy, dz * dz)); m2 = fminf(m2, d);
        dx = x3.x - px; dy = x3.y - py; dz = x3.z - pz;
        d = fmaf(dx, dx, fmaf(dy, dy, dz * dz)); m3 = fminf(m3, d);
    }
    const float dmin = fminf(fminf(m0, m1), fminf(m2, m3));
    const float am = assign[((size_t)b * NN + n0 + tid) * PP + p];
    float acc_pcl = dmin * am;

    // ---- cuboid term ----
    const float* nrb = nrm + ((size_t)bp * NN + n0) * 3;
    const float nx = nrb[tid * 3 + 0];
    const float ny = nrb[tid * 3 + 1];
    const float nz = nrb[tid * 3 + 2];
    float best = -nx; int idx = 0;
    if ( nx > best) { best =  nx; idx = 1; }
    if (-ny > best) { best = -ny; idx = 2; }
    if ( ny > best) { best =  ny; idx = 3; }
    if (-nz > best) { best = -nz; idx = 4; }
    if ( nz > best) { best =  nz; idx = 5; }
    const int c = idx >> 1;
    const float scc = (c == 0) ? sc0 : ((c == 1) ? sc1 : sc2);
    const float fv  = (idx & 1) ? scc : -scc;
    float pr0 = (c == 0) ? fv : fminf(fmaxf(px, -sc0), sc0);
    float pr1 = (c == 1) ? fv : fminf(fmaxf(py, -sc1), sc1);
    float pr2 = (c == 2) ? fv : fminf(fmaxf(pz, -sc2), sc2);
    float d0 = pr0 - px, d1 = pr1 - py, d2 = pr2 - pz;
    float acc_cub = fmaf(d0, d0, fmaf(d1, d1, d2 * d2)) * am;

    // ---- block-sum acc_pcl, acc_cub, am via wave shuffles ----
    {
        float s0 = wave_sum(acc_pcl);
        float s1 = wave_sum(acc_cub);
        float s2 = wave_sum(am);
        const int lane = tid & 63, wave = tid >> 6;
        if (lane == 0) {
            wsum[wave * 3 + 0] = s0;
            wsum[wave * 3 + 1] = s1;
            wsum[wave * 3 + 2] = s2;
        }
    }
    __syncthreads();

    // ---- Pass B: per-s min over this chunk ----
    {
        const int s    = tid & (SS - 1);
        const int half = tid >> 7;       // wave-uniform
        const float4 xv = Xs[s];
        const int nb0 = half * (CHUNK / 2);
        float b0 = 3.4e38f, b1 = 3.4e38f;
        #pragma unroll 4
        for (int n = 0; n < CHUNK / 2; n += 2) {
            float4 p0 = Pts[nb0 + n];
            float4 p1 = Pts[nb0 + n + 1];
            float dx, dy, dz, d;
            dx = xv.x - p0.x; dy = xv.y - p0.y; dz = xv.z - p0.z;
            d = fmaf(dx, dx, fmaf(dy, dy, dz * dz)); b0 = fminf(b0, d);
            dx = xv.x - p1.x; dy = xv.y - p1.y; dz = xv.z - p1.z;
            d = fmaf(dx, dx, fmaf(dy, dy, dz * dz)); b1 = fminf(b1, d);
        }
        red[tid] = fminf(b0, b1);
    }
    __syncthreads();

    float* part = ws + WS_PART + (size_t)(bp * NSPLIT + split) * PART_STRIDE;
    if (tid < SS) part[tid] = fminf(red[tid], red[tid + SS]);
    if (tid == 0) {
        part[SS + 0] = wsum[0] + wsum[3] + wsum[6] + wsum[9];
        part[SS + 1] = wsum[1] + wsum[4] + wsum[7] + wsum[10];
        part[SS + 2] = wsum[2] + wsum[5] + wsum[8] + wsum[11];
    }
}

// ---- Kernel 3: combine splits per bp (96 blocks x 128 threads) ----
__global__ __launch_bounds__(128) void superdec_reduce(
    const float* __restrict__ ws_in, float* __restrict__ ws_out)
{
    const int bp  = blockIdx.x;
    const int tid = threadIdx.x;
    __shared__ float sh[8];

    const float* base = ws_in + WS_PART + (size_t)bp * NSPLIT * PART_STRIDE;
    float m = 3.4e38f;
    #pragma unroll
    for (int sp = 0; sp < NSPLIT; ++sp)
        m = fminf(m, base[sp * PART_STRIDE + tid]);

    float s = wave_sum(m);
    const int lane = tid & 63, wave = tid >> 6;
    if (lane == 0) sh[wave] = s;
    if (tid < 3) {
        float acc = 0.f;
        #pragma unroll
        for (int sp = 0; sp < NSPLIT; ++sp)
            acc += base[sp * PART_STRIDE + SS + tid];
        sh[4 + tid] = acc;
    }
    __syncthreads();
    if (tid == 0) {
        float* o = ws_out + WS_BP + bp * 4;
        o[0] = sh[4];                       // pcl sum
        o[1] = sh[5];                       // cub sum
        o[2] = sh[6];                       // assign colsum
        o[3] = (sh[0] + sh[1]) / (float)SS; // prim2pcl mean over s
    }
}

// ---- Kernel 4: final scalar (1 block) ----
__global__ __launch_bounds__(128) void superdec_final(
    const float* __restrict__ ws, const float* __restrict__ exist,
    float* __restrict__ out)
{
    __shared__ float s_pcl[96], s_cub[96], s_pe[96], s_e[96], s_bce[96], s_sq[96];
    const int t = threadIdx.x;
    if (t < BB * PP) {
        const float* o = ws + WS_BP + t * 4;
        float pclv = o[0], cubv = o[1], colsum = o[2], prim = o[3];
        float e = exist[t];
        float gt = (colsum > 24.0f) ? 1.f : 0.f;
        s_pcl[t] = pclv;
        s_cub[t] = cubv;
        s_pe[t]  = prim * e;
        s_e[t]   = e;
        s_bce[t] = gt * logf(e) + (1.f - gt) * log1pf(-e);
        s_sq[t]  = sqrtf(colsum / (float)NN + 0.01f);
    }
    __syncthreads();
    if (t == 0) {
        float pcl_sum = 0.f, cub_sum = 0.f, bce_sum = 0.f;
        for (int i = 0; i < BB * PP; ++i) {
            pcl_sum += s_pcl[i]; cub_sum += s_cub[i]; bce_sum += s_bce[i];
        }
        float prim_loss = 0.f, sps = 0.f;
        for (int b = 0; b < BB; ++b) {
            float pe = 0.f, ee = 0.f, sq = 0.f;
            for (int p = 0; p < PP; ++p) {
                int i = b * PP + p;
                pe += s_pe[i]; ee += s_e[i]; sq += s_sq[i];
            }
            prim_loss += pe / (ee + 1e-6f);
            float mb = sq / (float)PP;
            sps += mb * mb;
        }
        prim_loss /= (float)BB;
        sps       /= (float)BB;
        float pcl_loss = pcl_sum / (float)(BB * NN);
        float cub      = cub_sum / (float)(BB * NN);
        float bce      = -bce_sum / (float)(BB * PP);
        out[0] = 0.1f * cub + 1.0f * (pcl_loss + prim_loss) + 0.01f * bce + 0.01f * sps;
    }
}

extern "C" void kernel_launch(void* const* d_in, const int* in_sizes, int n_in,
                              void* d_out, int out_size, void* d_ws, size_t ws_size,
                              hipStream_t stream) {
    const float* pc     = (const float*)d_in[0];
    const float* nrm    = (const float*)d_in[1];
    const float* scale  = (const float*)d_in[2];
    const float* shape  = (const float*)d_in[3];
    const float* exist  = (const float*)d_in[4];
    const float* assign = (const float*)d_in[5];
    const float* etas   = (const float*)d_in[6];
    const float* omegas = (const float*)d_in[7];
    float* ws  = (float*)d_ws;
    float* out = (float*)d_out;

    superdec_sample<<<BB * PP, SS, 0, stream>>>(scale, shape, etas, omegas, ws);
    superdec_main<<<BB * PP * NSPLIT, CHUNK, 0, stream>>>(pc, nrm, scale, assign, ws);
    superdec_reduce<<<BB * PP, SS, 0, stream>>>(ws, ws);
    superdec_final<<<1, 128, 0, stream>>>(ws, exist, out);
}